// Round 21
// baseline (56.487 us; speedup 1.0000x reference)
//
#include <hip/hip_runtime.h>
#include <math.h>

// GaussianMixtureLoss — R21: AMPLIFIED PROBE on R19 (sacrificial).
// j-loop repeated REP=8 (asm clobber stops folding); comb write scaled 1/REP
// so output is numerically identical. Decode: inner = (T - 15.97)/7;
// VALUBusy splits issue-bound vs stall-bound. Structure = R19 otherwise.
#define BATCH 4
#define NPTS 4096
#define NMIX 4096
#define THREADS 256
#define PPB 32
#define PTS 8
#define NPAIR (NMIX / 2)      // 2048 pairs staged once (64 KB)
#define JITER (NPAIR / 64)    // 32
#define NBLOCKS ((BATCH * NPTS) / PPB)  // 512
#define REP 8

#define LN2 0.6931471805599453f
#define CONST_TERM 0.9189385332046727f
#define INV_COUNT (1.0f / (float)(BATCH * NPTS))
#define SEXP_K    12102203.0f
#define SEXP_BIAS 1.06488094e9f

typedef float v2f __attribute__((ext_vector_type(2)));

__device__ __forceinline__ float fast_log2(float x) {
#if __has_builtin(__builtin_amdgcn_logf)
  return __builtin_amdgcn_logf(x);
#else
  return log2f(x);
#endif
}

__device__ __forceinline__ v2f pk_fma(v2f a, v2f b, v2f c) {
  v2f d;
  asm("v_pk_fma_f32 %0, %1, %2, %3" : "=v"(d) : "v"(a), "v"(b), "v"(c));
  return d;
}

__global__ __launch_bounds__(THREADS) void gm_main(
    const float* __restrict__ pred, const float* __restrict__ gt,
    float* __restrict__ bsum) {
  __shared__ float4 gsh[2 * NPAIR];  // 64 KB
  __shared__ float wpart[4][32];
  float* comb = (float*)gsh;         // aliased tail buffer [64][33]

  const int t = threadIdx.x;
  const int b = blockIdx.x >> 7;
  const int n0 = (blockIdx.x & 127) * PPB;
  const int pl = t & 3;
  const int ml = t >> 2;

  v2f px2[PTS], py2[PTS], pz2[PTS], acc[PTS];
#pragma unroll
  for (int k = 0; k < PTS; ++k) {
    const float* p = pred + ((size_t)(b * NPTS + n0 + pl * PTS + k)) * 3;
    px2[k] = (v2f){p[0], p[0]};
    py2[k] = (v2f){p[1], p[1]};
    pz2[k] = (v2f){p[2], p[2]};
    acc[k] = (v2f){0.f, 0.f};
  }

  // single-pass stage (R19)
#pragma unroll
  for (int i = 0; i < NPAIR / THREADS; ++i) {
    int s = t + i * THREADS;
    const float2* g = (const float2*)(gt + ((size_t)(b * NMIX + 2 * s)) * 3);
    float2 g01 = g[0], g23 = g[1], g45 = g[2];
    float n20 = fmaf(g01.x, g01.x, fmaf(g01.y, g01.y, g23.x * g23.x));
    float n21 = fmaf(g23.y, g23.y, fmaf(g45.x, g45.x, g45.y * g45.y));
    gsh[2 * s]     = make_float4(SEXP_K * g01.x, SEXP_K * g23.y,
                                 SEXP_K * g01.y, SEXP_K * g45.x);
    gsh[2 * s + 1] = make_float4(SEXP_K * g23.x, SEXP_K * g45.y,
                                 fmaf(n20, -0.5f * SEXP_K, SEXP_BIAS),
                                 fmaf(n21, -0.5f * SEXP_K, SEXP_BIAS));
  }
  __syncthreads();

#pragma unroll 1
  for (int rep = 0; rep < REP; ++rep) {
    asm volatile("" ::: "memory");  // prevent folding of identical passes
    const float4* gbase = gsh + 2 * ml;
#pragma unroll 8
    for (int j = 0; j < JITER; ++j) {
      float4 a = gbase[128 * j];
      float4 c4 = gbase[128 * j + 1];
      v2f gx2 = (v2f){a.x, a.y}, gy2 = (v2f){a.z, a.w};
      v2f gz2 = (v2f){c4.x, c4.y}, w2 = (v2f){c4.z, c4.w};
#pragma unroll
      for (int k = 0; k < PTS; ++k) {
        v2f d = pk_fma(pz2[k], gz2, w2);
        d = pk_fma(py2[k], gy2, d);
        d = pk_fma(px2[k], gx2, d);
        v2f e;
        e.x = __builtin_bit_cast(float, (int)d.x);
        e.y = __builtin_bit_cast(float, (int)d.y);
        acc[k] += e;
      }
    }
  }

  __syncthreads();

#pragma unroll
  for (int k = 0; k < PTS; ++k)
    comb[ml * (PPB + 1) + pl * PTS + k] =
        (acc[k].x + acc[k].y) * (1.0f / (float)REP);
  __syncthreads();

  {
    const int col = t & 31, grp = t >> 5;
    float s = 0.f;
#pragma unroll
    for (int r = 0; r < 8; ++r) s += comb[(grp * 8 + r) * (PPB + 1) + col];
    s += __shfl_down(s, 32, 64);
    if ((t & 63) < 32) wpart[t >> 6][col] = s;
  }
  __syncthreads();

  if (t < 32) {
    float s = (wpart[0][t] + wpart[1][t]) + (wpart[2][t] + wpart[3][t]);
    const float* p = pred + ((size_t)(b * NPTS + n0 + t)) * 3;
    float hp2 = 0.5f * (p[0] * p[0] + p[1] * p[1] + p[2] * p[2]);
    float ll = (LN2 * fast_log2(s) - hp2) * INV_COUNT;
#pragma unroll
    for (int off = 16; off > 0; off >>= 1) ll += __shfl_down(ll, off, 32);
    if (t == 0) bsum[blockIdx.x] = ll;
  }
}

__global__ __launch_bounds__(THREADS) void gm_reduce(
    const float* __restrict__ bsum, float* __restrict__ out) {
  const int t = threadIdx.x;
  float v = bsum[t] + bsum[t + 256];
  for (int off = 32; off > 0; off >>= 1) v += __shfl_down(v, off, 64);
  __shared__ float w[4];
  if ((t & 63) == 0) w[t >> 6] = v;
  __syncthreads();
  if (t == 0) out[0] = CONST_TERM - ((w[0] + w[1]) + (w[2] + w[3]));
}

extern "C" void kernel_launch(void* const* d_in, const int* in_sizes, int n_in,
                              void* d_out, int out_size, void* d_ws, size_t ws_size,
                              hipStream_t stream) {
  const float* pred = (const float*)d_in[0];
  const float* gt   = (const float*)d_in[1];
  float* out = (float*)d_out;
  float* bsum = (float*)d_ws;

  gm_main<<<NBLOCKS, THREADS, 0, stream>>>(pred, gt, bsum);
  gm_reduce<<<1, THREADS, 0, stream>>>(bsum, out);
}

// Round 22
// 15.984 us; speedup vs baseline: 3.5340x; 3.5340x over previous
//
#include <hip/hip_runtime.h>
#include <math.h>

// GaussianMixtureLoss: loss = CONST - mean_{b,n}( ln sum_m exp(p·g - |g|²/2) - |p|²/2 )
// B=4, N=4096, M=4096, D=3, SIGMA=1.
// R22: R19 + double occupancy. R21 probe: inner 5.8us vs 3.0 issue floor,
// VALUBusy 70% at 2 waves/SIMD -> ~30% latency stall. This config:
// 512 blocks x 512 threads, 64KB single-pass LDS -> 2 blocks/CU x 8 waves
// = 4 waves/SIMD (VGPR ~70 ok). Per-thread = 4 pts x 2 mixtures x 32 j.
// Inner math/staging transform byte-identical to R19. Bank conflicts
// measured negligible (2^18 cyc/dispatch) - not a factor.
#define BATCH 4
#define NPTS 4096
#define NMIX 4096
#define THREADS 512
#define PPB 32                // points per block
#define PTS 4                 // points per thread
#define NPAIR (NMIX / 2)      // 2048 mixture pairs, staged once (64 KB)
#define JITER (NPAIR / 64)    // 32 j-iters (64 mixture-pair lanes)
#define NBLOCKS ((BATCH * NPTS) / PPB)  // 512

#define LN2 0.6931471805599453f
#define CONST_TERM 0.9189385332046727f  // 0.5*log(2*pi)
#define INV_COUNT (1.0f / (float)(BATCH * NPTS))
// Schraudolph folded: K = 2^23*log2(e); BIAS = 2^23*(127-0.0563)
#define SEXP_K    12102203.0f
#define SEXP_BIAS 1.06488094e9f

typedef float v2f __attribute__((ext_vector_type(2)));

__device__ __forceinline__ float fast_log2(float x) {
#if __has_builtin(__builtin_amdgcn_logf)
  return __builtin_amdgcn_logf(x);
#else
  return log2f(x);
#endif
}

__device__ __forceinline__ v2f pk_fma(v2f a, v2f b, v2f c) {
  v2f d;
  asm("v_pk_fma_f32 %0, %1, %2, %3" : "=v"(d) : "v"(a), "v"(b), "v"(c));
  return d;
}

__global__ __launch_bounds__(THREADS) void gm_main(
    const float* __restrict__ pred, const float* __restrict__ gt,
    float* __restrict__ bsum) {
  __shared__ float4 gsh[2 * NPAIR];  // 64 KB (2048 pairs x 2 float4)
  __shared__ float wpart[8][32];     // [wave][point col] : 1 KB
  float* comb = (float*)gsh;         // aliased tail buffer [64][33]

  const int t = threadIdx.x;
  const int b = blockIdx.x >> 7;             // 128 blocks per batch
  const int n0 = (blockIdx.x & 127) * PPB;
  const int pl = t & 7;                      // point group 0..7 (4 pts each)
  const int ml = t >> 3;                     // mixture-pair lane 0..63

  // 4 scalar points, hoisted as broadcast pairs for pk_fma
  v2f px2[PTS], py2[PTS], pz2[PTS], acc[PTS];
#pragma unroll
  for (int k = 0; k < PTS; ++k) {
    const float* p = pred + ((size_t)(b * NPTS + n0 + pl * PTS + k)) * 3;
    px2[k] = (v2f){p[0], p[0]};
    py2[k] = (v2f){p[1], p[1]};
    pz2[k] = (v2f){p[2], p[2]};
    acc[k] = (v2f){0.f, 0.f};
  }

  // single-pass stage: all 2048 pairs, no pre-barrier (no prior readers)
#pragma unroll
  for (int i = 0; i < NPAIR / THREADS; ++i) {
    int s = t + i * THREADS;  // pair index 0..2047
    const float2* g = (const float2*)(gt + ((size_t)(b * NMIX + 2 * s)) * 3);
    float2 g01 = g[0], g23 = g[1], g45 = g[2];
    // mixture 2s: (g01.x, g01.y, g23.x); 2s+1: (g23.y, g45.x, g45.y)
    float n20 = fmaf(g01.x, g01.x, fmaf(g01.y, g01.y, g23.x * g23.x));
    float n21 = fmaf(g23.y, g23.y, fmaf(g45.x, g45.x, g45.y * g45.y));
    gsh[2 * s]     = make_float4(SEXP_K * g01.x, SEXP_K * g23.y,
                                 SEXP_K * g01.y, SEXP_K * g45.x);
    gsh[2 * s + 1] = make_float4(SEXP_K * g23.x, SEXP_K * g45.y,
                                 fmaf(n20, -0.5f * SEXP_K, SEXP_BIAS),
                                 fmaf(n21, -0.5f * SEXP_K, SEXP_BIAS));
  }
  __syncthreads();

  {
    const float4* gbase = gsh + 2 * ml;  // per-j offsets are immediates
#pragma unroll 8
    for (int j = 0; j < JITER; ++j) {
      float4 a = gbase[128 * j];      // {Kgx0,Kgx1,Kgy0,Kgy1}
      float4 c4 = gbase[128 * j + 1]; // {Kgz0,Kgz1,w0,w1}
      v2f gx2 = (v2f){a.x, a.y}, gy2 = (v2f){a.z, a.w};
      v2f gz2 = (v2f){c4.x, c4.y}, w2 = (v2f){c4.z, c4.w};
#pragma unroll
      for (int k = 0; k < PTS; ++k) {
        v2f d = pk_fma(pz2[k], gz2, w2);
        d = pk_fma(py2[k], gy2, d);
        d = pk_fma(px2[k], gx2, d);
        v2f e;                                    // Schraudolph exp, packed
        e.x = __builtin_bit_cast(float, (int)d.x);
        e.y = __builtin_bit_cast(float, (int)d.y);
        acc[k] += e;
      }
    }
  }

  __syncthreads();  // all gsh reads done before aliasing as comb

  // comb[ml][pl*4+k]: both mixture halves pre-summed; [64][33] padded
#pragma unroll
  for (int k = 0; k < PTS; ++k)
    comb[ml * (PPB + 1) + pl * PTS + k] = acc[k].x + acc[k].y;
  __syncthreads();

  {
    const int col = t & 31, grp = t >> 5;  // 16 groups x 4 rows
    float s = 0.f;
#pragma unroll
    for (int r = 0; r < 4; ++r) s += comb[(grp * 4 + r) * (PPB + 1) + col];
    // wave w covers grps {2w,2w+1}; fold the upper half onto lanes 0-31
    s += __shfl_down(s, 32, 64);
    if ((t & 63) < 32) wpart[t >> 6][col] = s;
  }
  __syncthreads();

  if (t < 32) {
    float s = ((wpart[0][t] + wpart[1][t]) + (wpart[2][t] + wpart[3][t])) +
              ((wpart[4][t] + wpart[5][t]) + (wpart[6][t] + wpart[7][t]));
    const float* p = pred + ((size_t)(b * NPTS + n0 + t)) * 3;
    float hp2 = 0.5f * (p[0] * p[0] + p[1] * p[1] + p[2] * p[2]);
    float ll = (LN2 * fast_log2(s) - hp2) * INV_COUNT;
#pragma unroll
    for (int off = 16; off > 0; off >>= 1) ll += __shfl_down(ll, off, 32);
    if (t == 0) bsum[blockIdx.x] = ll;
  }
}

__global__ __launch_bounds__(256) void gm_reduce(
    const float* __restrict__ bsum, float* __restrict__ out) {
  const int t = threadIdx.x;
  float v = bsum[t] + bsum[t + 256];  // 512 entries
  for (int off = 32; off > 0; off >>= 1) v += __shfl_down(v, off, 64);
  __shared__ float w[4];
  if ((t & 63) == 0) w[t >> 6] = v;
  __syncthreads();
  if (t == 0) out[0] = CONST_TERM - ((w[0] + w[1]) + (w[2] + w[3]));
}

extern "C" void kernel_launch(void* const* d_in, const int* in_sizes, int n_in,
                              void* d_out, int out_size, void* d_ws, size_t ws_size,
                              hipStream_t stream) {
  const float* pred = (const float*)d_in[0];
  const float* gt   = (const float*)d_in[1];
  float* out = (float*)d_out;
  float* bsum = (float*)d_ws;  // 512 floats, fully overwritten every call

  gm_main<<<NBLOCKS, THREADS, 0, stream>>>(pred, gt, bsum);
  gm_reduce<<<1, 256, 0, stream>>>(bsum, out);
}

// Round 23
// 15.032 us; speedup vs baseline: 3.7579x; 1.0633x over previous
//
#include <hip/hip_runtime.h>
#include <hip/hip_fp16.h>
#include <math.h>

// GaussianMixtureLoss: loss = CONST - mean_{b,n}( ln sum_m exp(p·g - |g|²/2) - |p|²/2 )
// B=4, N=4096, M=4096, D=3, SIGMA=1.
// R23: MFMA inner loop. R21/R22 proved the scalar path is VALU-datapath
// bound (5 ops/exp, 4.3us floor, 74% achieved). Move the K=4 dot to the
// IDLE matrix pipe via v_mfma_f32_32x32x8_f16:
//   point quad (sqrtK*p, 32768), mixture quad (sqrtK*g, a4),
//   a4 = BIAS/32768 - (K/65536)|g|^2  ->  dot = K(p.g) + BIAS - K/2|g|^2
//   = Schraudolph domain directly. VALU keeps only cvt+add (2 ops/exp).
// Lanes 0-31 carry k=0-3 (real), lanes 32-63 k=4-7 (zeroed) - free K pad.
// A-frag (points) loop-invariant; B-frag = 1 ds_read_b64 + 2 cndmask/tile.
// f16 rounding: +-2-3% per term, zero-mean -> loss (mean of 16K pts) err
// ~1e-3 << 0.112 threshold. C/D layout per m74/m101.
#define BATCH 4
#define NPTS 4096
#define NMIX 4096
#define THREADS 512
#define PPB 32                 // points per block (one 32-row MFMA tile)
#define NBLOCKS ((BATCH * NPTS) / PPB)  // 512
#define NTILES (NMIX / 32)     // 128 mixture tiles per batch
#define TPW (NTILES / 8)       // 16 tiles per wave (8 waves)

#define LN2 0.6931471805599453f
#define CONST_TERM 0.9189385332046727f  // 0.5*log(2*pi)
#define INV_COUNT (1.0f / (float)(BATCH * NPTS))
// Schraudolph: K = 2^23*log2(e) = 12102203.16; BIAS = 2^23*(127-0.0563)
#define SQK      3478.8221f          // sqrt(K)
#define B4VAL    32768.0f            // exact in f16
#define A4BASE   32497.587f          // BIAS / 32768
#define A4SLOPE  (-184.66497f)       // -(K/2) / 32768

typedef _Float16 f16x4 __attribute__((ext_vector_type(4)));
typedef float f32x16 __attribute__((ext_vector_type(16)));

__device__ __forceinline__ float fast_log2(float x) {
#if __has_builtin(__builtin_amdgcn_logf)
  return __builtin_amdgcn_logf(x);
#else
  return log2f(x);
#endif
}

__device__ __forceinline__ uint32_t pack_h2(float a, float b) {
  __half2 h = __float22half2_rn(make_float2(a, b));
  return __builtin_bit_cast(uint32_t, h);
}

__global__ __launch_bounds__(THREADS) void gm_main(
    const float* __restrict__ pred, const float* __restrict__ gt,
    float* __restrict__ bsum) {
  __shared__ __align__(8) uint2 gsh[NMIX];  // 32 KB: mixture f16 quads
  __shared__ float comb[8][PPB];            // 1 KB: per-wave partial rows
  __shared__ float wred[16];

  const int t = threadIdx.x;
  const int b = blockIdx.x >> 7;            // 128 blocks per batch
  const int n0 = (blockIdx.x & 127) * PPB;
  const int lane = t & 63;
  const int w = t >> 6;                     // wave 0..7

  // ---- stage mixture table: quad (sqrtK*g, a4) as 4xf16 = 8 B ----
#pragma unroll
  for (int i = 0; i < NMIX / THREADS; ++i) {  // 8 per thread
    int m = t + i * THREADS;
    const float* g = gt + (size_t)(b * NMIX + m) * 3;
    float gx = g[0], gy = g[1], gz = g[2];
    float n2 = fmaf(gx, gx, fmaf(gy, gy, gz * gz));
    float a4 = fmaf(n2, A4SLOPE, A4BASE);
    gsh[m] = make_uint2(pack_h2(SQK * gx, SQK * gy), pack_h2(SQK * gz, a4));
  }

  // ---- A-frag (points), loop-invariant: lane<32 -> point n0+lane ----
  f16x4 afrag;
  {
    uint2 au = make_uint2(0u, 0u);
    if (lane < 32) {
      const float* p = pred + (size_t)(b * NPTS + n0 + lane) * 3;
      au = make_uint2(pack_h2(SQK * p[0], SQK * p[1]),
                      pack_h2(SQK * p[2], B4VAL));
    }
    afrag = __builtin_bit_cast(f16x4, au);
  }

  __syncthreads();

  // ---- inner: 16 mixture tiles per wave, MFMA + Schraudolph cvt/add ----
  f32x16 acc = 0.0f;
  {
    const uint2* bbase = gsh + w * (TPW * 32) + (lane & 31);
    const bool lo = lane < 32;
    const f32x16 czero = 0.0f;
#pragma unroll 4
    for (int j = 0; j < TPW; ++j) {
      uint2 raw = bbase[j * 32];            // ds_read_b64; upper lanes = broadcast dup
      raw.x = lo ? raw.x : 0u;              // zero k=4..7 lanes
      raw.y = lo ? raw.y : 0u;
      f16x4 bfrag = __builtin_bit_cast(f16x4, raw);
      f32x16 d = __builtin_amdgcn_mfma_f32_32x32x8f16(afrag, bfrag, czero, 0, 0, 0);
#pragma unroll
      for (int r = 0; r < 16; ++r)
        acc[r] += __builtin_bit_cast(float, (int)d[r]);  // Schraudolph exp
    }
  }

  // ---- col-reduce: sum the 32 mixture-cols (xor over lane bits 0-4) ----
#pragma unroll
  for (int mask = 1; mask <= 16; mask <<= 1) {
#pragma unroll
    for (int r = 0; r < 16; ++r) acc[r] += __shfl_xor(acc[r], mask, 64);
  }

  // rows: (r&3) + 8*(r>>2) + 4*(lane>>5); lanes 0 and 32 write 16 rows each
  if ((lane & 31) == 0) {
#pragma unroll
    for (int r = 0; r < 16; ++r)
      comb[w][(r & 3) + 8 * (r >> 2) + 4 * (lane >> 5)] = acc[r];
  }
  __syncthreads();

  // ---- tail: combine 8 waves, log, hp2, block reduce ----
  if (t < PPB) {
    float s = ((comb[0][t] + comb[1][t]) + (comb[2][t] + comb[3][t])) +
              ((comb[4][t] + comb[5][t]) + (comb[6][t] + comb[7][t]));
    const float* p = pred + (size_t)(b * NPTS + n0 + t) * 3;
    float hp2 = 0.5f * (p[0] * p[0] + p[1] * p[1] + p[2] * p[2]);
    float ll = (LN2 * fast_log2(s) - hp2) * INV_COUNT;
#pragma unroll
    for (int off = 16; off > 0; off >>= 1) ll += __shfl_down(ll, off, 32);
    if (t == 0) bsum[blockIdx.x] = ll;
  }
}

__global__ __launch_bounds__(256) void gm_reduce(
    const float* __restrict__ bsum, float* __restrict__ out) {
  const int t = threadIdx.x;
  float v = bsum[t] + bsum[t + 256];  // 512 entries
  for (int off = 32; off > 0; off >>= 1) v += __shfl_down(v, off, 64);
  __shared__ float w[4];
  if ((t & 63) == 0) w[t >> 6] = v;
  __syncthreads();
  if (t == 0) out[0] = CONST_TERM - ((w[0] + w[1]) + (w[2] + w[3]));
}

extern "C" void kernel_launch(void* const* d_in, const int* in_sizes, int n_in,
                              void* d_out, int out_size, void* d_ws, size_t ws_size,
                              hipStream_t stream) {
  const float* pred = (const float*)d_in[0];
  const float* gt   = (const float*)d_in[1];
  float* out = (float*)d_out;
  float* bsum = (float*)d_ws;  // 512 floats, fully overwritten every call

  gm_main<<<NBLOCKS, THREADS, 0, stream>>>(pred, gt, bsum);
  gm_reduce<<<1, 256, 0, stream>>>(bsum, out);
}